// Round 16
// baseline (405.417 us; speedup 1.0000x reference)
//
#include <hip/hip_runtime.h>
#include <hip/hip_cooperative_groups.h>
#include <hip/hip_bf16.h>

namespace cg = cooperative_groups;

#define N_NODES 4096            // row key == global src node id (g<<7)|r
#define N_PER   128
#define D_DIM   64
#define CELLS   (N_NODES * N_PER)   // 524288
#define CAP     12              // per-cell edge capacity; Poisson(0.25), P(>12)~1e-12

// ---------------- cooperative fused kernel (grid-size agnostic) -------------
// Phase 1: zero cnt_pack + projection p1/p2. Phase 2: link. Phase 3: row_write.
__global__ void __launch_bounds__(256, 4)
fused(const float* __restrict__ x,
      const int* __restrict__ esrc, const int* __restrict__ edst,
      const int* __restrict__ tsrc, const int* __restrict__ tdst,
      const float* __restrict__ W, const float* __restrict__ b,
      const float4* __restrict__ attr4,
      float* __restrict__ p1, float* __restrict__ p2,
      int* __restrict__ cnt_pack, int* __restrict__ cslots,
      float4* __restrict__ out4, int E, int total)
{
    cg::grid_group grid = cg::this_grid();
    const int tid     = threadIdx.x;
    const int nthread = gridDim.x * 256;
    const int gi0     = blockIdx.x * 256 + tid;

    // ---- Phase 1: zero cnt_pack (int4) + projection (one wave per node) ----
    for (int i = gi0; i < CELLS / 4; i += nthread)
        ((int4*)cnt_pack)[i] = make_int4(0, 0, 0, 0);
    {
        const int nwaves = nthread >> 6;
        const int wid0   = gi0 >> 6;
        const int d      = tid & 63;
        for (int n = wid0; n < N_NODES; n += nwaves) {
            const float* xr = x + (size_t)n * D_DIM;
            const float* wt = W + (size_t)d * (2 * D_DIM);
            float a1 = b[d];
            float a2 = 0.0f;
#pragma unroll
            for (int kk = 0; kk < D_DIM; ++kk) {
                float xv = xr[kk];
                a1 += xv * wt[kk];
                a2 += xv * wt[D_DIM + kk];
            }
            p1[(size_t)n * D_DIM + d] = a1;
            p2[(size_t)n * D_DIM + d] = a2;
        }
    }
    grid.sync();

    // ---- Phase 2: link (one thread per edge/token) ----
    for (int i = gi0; i < total; i += nthread) {
        if (i < E) {
            int cell = (esrc[i] << 7) | (edst[i] & 127);
            int old = atomicAdd(&cnt_pack[cell], 0x10000);
            int slot = old >> 16;
            if (slot < CAP) cslots[(size_t)cell * CAP + slot] = i;
        } else {
            int j = i - E;
            int cell = (tsrc[j] << 7) | (tdst[j] & 127);
            atomicAdd(&cnt_pack[cell], 1);
        }
    }
    grid.sync();

    // ---- Phase 3: row_write (one block per row, grid-strided) ----
    const int lane   = tid & 63;
    const int grp    = (tid >> 4) & 3;
    const int lane16 = tid & 15;
    const int wave   = tid >> 6;
    const int cbase  = wave * 32;

    for (int k = blockIdx.x; k < N_NODES; k += gridDim.x) {
        const int gbase = k & ~127;            // g<<7

        int cv = cnt_pack[(k << 7) + cbase + (lane & 31)];
        float4 p1v = ((const float4*)p1)[(size_t)k * 16 + lane16];

        float4 p2v[8];
#pragma unroll
        for (int it = 0; it < 8; ++it) {
            int c = cbase + it * 4 + grp;
            p2v[it] = ((const float4*)p2)[(size_t)(gbase | c) * 16 + lane16];
        }

#pragma unroll
        for (int it = 0; it < 8; ++it) {
            int c    = cbase + it * 4 + grp;
            int cell = (k << 7) | c;
            int pk   = __shfl(cv, it * 4 + grp, 64);
            float f  = (float)(pk & 0xFFFF);
            float4 v;
            v.x = f * (p1v.x + p2v[it].x);
            v.y = f * (p1v.y + p2v[it].y);
            v.z = f * (p1v.z + p2v[it].z);
            v.w = f * (p1v.w + p2v[it].w);
            int n = pk >> 16;
            if (n > CAP) n = CAP;
            const int* sl = cslots + (size_t)cell * CAP;
            for (int i = 0; i < n; ++i) {
                int e = sl[i];
                float4 a = attr4[(size_t)e * 16 + lane16];
                v.x += a.x; v.y += a.y; v.z += a.z; v.w += a.w;
            }
            out4[(size_t)cell * 16 + lane16] = v;
        }
    }
}

// ---------------- fallback: proven R13 three-kernel pipeline ----------------
__global__ void init_proj(int4* __restrict__ cp4,
                          const float* __restrict__ x,
                          const float* __restrict__ W,
                          const float* __restrict__ b,
                          float* __restrict__ p1,
                          float* __restrict__ p2) {
    if (blockIdx.x < 512) {
        int i = blockIdx.x * 256 + threadIdx.x;
        cp4[i] = make_int4(0, 0, 0, 0);
    } else {
        int n = (blockIdx.x - 512) * 4 + (threadIdx.x >> 6);
        int d = threadIdx.x & 63;
        const float* xr = x + (size_t)n * D_DIM;
        const float* w  = W + (size_t)d * (2 * D_DIM);
        float a1 = b[d];
        float a2 = 0.0f;
#pragma unroll
        for (int k = 0; k < D_DIM; ++k) {
            float xv = xr[k];
            a1 += xv * w[k];
            a2 += xv * w[D_DIM + k];
        }
        p1[(size_t)n * D_DIM + d] = a1;
        p2[(size_t)n * D_DIM + d] = a2;
    }
}

__global__ void link(const int* __restrict__ esrc,
                     const int* __restrict__ edst,
                     const int* __restrict__ tsrc,
                     const int* __restrict__ tdst,
                     int* __restrict__ cnt_pack,
                     int* __restrict__ cslots,
                     int E, int total) {
    int i = blockIdx.x * blockDim.x + threadIdx.x;
    if (i >= total) return;
    if (i < E) {
        int cell = (esrc[i] << 7) | (edst[i] & 127);
        int old = atomicAdd(&cnt_pack[cell], 0x10000);
        int slot = old >> 16;
        if (slot < CAP) cslots[(size_t)cell * CAP + slot] = i;
    } else {
        int j = i - E;
        int cell = (tsrc[j] << 7) | (tdst[j] & 127);
        atomicAdd(&cnt_pack[cell], 1);
    }
}

__global__ void __launch_bounds__(256, 4)
row_write(const int* __restrict__ cnt_pack,
          const int* __restrict__ cslots,
          const float4* __restrict__ attr4,
          const float4* __restrict__ p14,
          const float4* __restrict__ p24,
          float4* __restrict__ out4) {
    const int k      = blockIdx.x;
    const int gbase  = k & ~127;
    const int lane   = threadIdx.x & 63;
    const int grp    = (threadIdx.x >> 4) & 3;
    const int lane16 = threadIdx.x & 15;
    const int wave   = threadIdx.x >> 6;
    const int cbase  = wave * 32;

    int cv = cnt_pack[(k << 7) + cbase + (lane & 31)];
    float4 p1v = p14[(size_t)k * 16 + lane16];

    float4 p2v[8];
#pragma unroll
    for (int it = 0; it < 8; ++it) {
        int c = cbase + it * 4 + grp;
        p2v[it] = p24[(size_t)(gbase | c) * 16 + lane16];
    }

#pragma unroll
    for (int it = 0; it < 8; ++it) {
        int c    = cbase + it * 4 + grp;
        int cell = (k << 7) | c;
        int pk   = __shfl(cv, it * 4 + grp, 64);
        float f  = (float)(pk & 0xFFFF);
        float4 v;
        v.x = f * (p1v.x + p2v[it].x);
        v.y = f * (p1v.y + p2v[it].y);
        v.z = f * (p1v.z + p2v[it].z);
        v.w = f * (p1v.w + p2v[it].w);
        int n = pk >> 16;
        if (n > CAP) n = CAP;
        const int* sl = cslots + (size_t)cell * CAP;
        for (int i = 0; i < n; ++i) {
            int e = sl[i];
            float4 a = attr4[(size_t)e * 16 + lane16];
            v.x += a.x; v.y += a.y; v.z += a.z; v.w += a.w;
        }
        out4[(size_t)cell * 16 + lane16] = v;
    }
}

extern "C" void kernel_launch(void* const* d_in, const int* in_sizes, int n_in,
                              void* d_out, int out_size, void* d_ws, size_t ws_size,
                              hipStream_t stream) {
    const float* x           = (const float*)d_in[0];
    const int*   edge_index  = (const int*)d_in[1];
    const float* edge_attr   = (const float*)d_in[2];
    // d_in[3] = batch (unused: indices are intra-graph with N_PER=128 stride)
    const int*   token_index = (const int*)d_in[4];
    const float* W           = (const float*)d_in[5];
    const float* b           = (const float*)d_in[6];

    int E = in_sizes[1] / 2;   // 131072
    int T = in_sizes[4] / 2;   // 131072
    int total = E + T;

    // Workspace layout (~28 MB of the 512 MiB ws):
    float* p1       = (float*)d_ws;                          // 1 MB
    float* p2       = p1 + (size_t)N_NODES * D_DIM;          // 1 MB
    int*   cnt_pack = (int*)(p2 + (size_t)N_NODES * D_DIM);  // 2 MB
    int*   cslots   = cnt_pack + CELLS;                      // 24 MB

    const int* e0 = edge_index;
    const int* e1 = edge_index + E;
    const int* t0 = token_index;
    const int* t1 = token_index + T;
    const float4* attr4 = (const float4*)edge_attr;
    float4* out4 = (float4*)d_out;

    void* args[] = {
        (void*)&x, (void*)&e0, (void*)&e1, (void*)&t0, (void*)&t1,
        (void*)&W, (void*)&b, (void*)&attr4,
        (void*)&p1, (void*)&p2, (void*)&cnt_pack, (void*)&cslots,
        (void*)&out4, (void*)&E, (void*)&total
    };

    // Try cooperative fusion at decreasing grid sizes; fall back to the
    // proven 3-kernel pipeline if cooperative launch is rejected.
    hipError_t err = hipLaunchCooperativeKernel((void*)fused, dim3(1024),
                                                dim3(256), args, 0, stream);
    if (err != hipSuccess)
        err = hipLaunchCooperativeKernel((void*)fused, dim3(512),
                                         dim3(256), args, 0, stream);
    if (err != hipSuccess)
        err = hipLaunchCooperativeKernel((void*)fused, dim3(256),
                                         dim3(256), args, 0, stream);
    if (err != hipSuccess) {
        init_proj<<<1536, 256, 0, stream>>>((int4*)cnt_pack, x, W, b, p1, p2);
        link<<<(total + 255) / 256, 256, 0, stream>>>(
            e0, e1, t0, t1, cnt_pack, cslots, E, total);
        row_write<<<N_NODES, 256, 0, stream>>>(
            cnt_pack, cslots, attr4,
            (const float4*)p1, (const float4*)p2, out4);
    }
}